// Round 14
// baseline (95.225 us; speedup 1.0000x reference)
//
#include <hip/hip_runtime.h>
#include <hip/hip_bf16.h>

#define D_MODEL 512
#define N_HEADS 8
#define HEAD_DIM 64
#define BATCH 4
#define SEQ 2048

typedef _Float16 f16;
typedef _Float16 f16x8 __attribute__((ext_vector_type(8)));
typedef _Float16 f16x4 __attribute__((ext_vector_type(4)));
typedef float f32x4 __attribute__((ext_vector_type(4)));
typedef unsigned int u32x4 __attribute__((ext_vector_type(4)));

#define MFMA16(a, b, c) __builtin_amdgcn_mfma_f32_16x16x32_f16((a), (b), (c), 0, 0, 0)

#define GLOAD_LDS16(src, dst)                                                   \
    __builtin_amdgcn_global_load_lds(                                           \
        (const __attribute__((address_space(1))) void*)(src),                   \
        (__attribute__((address_space(3))) void*)(dst), 16, 0, 0)

#if __has_builtin(__builtin_amdgcn_exp2f)
#define EXP2(x) __builtin_amdgcn_exp2f(x)
#else
#define EXP2(x) __expf((x) * 0.6931471805599453f)
#endif

// Q pre-scale: 1/sqrt(64) * log2(e)  (scores produced in log2 domain)
#define QSCALE 0.18033688011112042f
// softmax offset: 6 * log2(e)
#define OFF2 8.656170245333781f

// ---------------------------------------------------------------------------
// weights fp32 -> f16 (hi only): Wq, Wk, Wv, Wo
// ---------------------------------------------------------------------------
__global__ __launch_bounds__(256) void wsplit(
    const float* __restrict__ w0, const float* __restrict__ w1,
    const float* __restrict__ w2, const float* __restrict__ w3,
    f16* __restrict__ h0, f16* __restrict__ h1,
    f16* __restrict__ h2, f16* __restrict__ h3)
{
    const int j = blockIdx.y;
    const float* s = (j == 0) ? w0 : (j == 1) ? w1 : (j == 2) ? w2 : w3;
    f16* dh = (j == 0) ? h0 : (j == 1) ? h1 : (j == 2) ? h2 : h3;
    const int n4 = (D_MODEL * D_MODEL) >> 2;
    for (int i = blockIdx.x * 256 + threadIdx.x; i < n4; i += gridDim.x * 256) {
        float4 x = ((const float4*)s)[i];
        f16x4 hv = {(f16)x.x, (f16)x.y, (f16)x.z, (f16)x.w};
        ((f16x4*)dh)[i] = hv;
    }
}

// ---------------------------------------------------------------------------
// QKV projection (r9 config: BM=128/BN=128, 256 thr, grid 768 = 3 blocks/CU,
// A reg-staged fp32->f16, W f16 via global_load_lds).
// ---------------------------------------------------------------------------
__global__ __launch_bounds__(256, 3) void proj_mfma(
    const float* __restrict__ Xq, const float* __restrict__ Xk,
    const float* __restrict__ Xv,
    const f16* __restrict__ Wqh, const f16* __restrict__ Wkh,
    const f16* __restrict__ Wvh,
    const float* __restrict__ bq, const float* __restrict__ bk,
    const float* __restrict__ bv,
    f16* __restrict__ Qh, f16* __restrict__ Kh, f16* __restrict__ Vt)
{
    __shared__ f16 ldsA[128 * 64];
    __shared__ f16 ldsW[128 * 64];

    const int z = blockIdx.z;
    const float* X = (z == 0) ? Xq : (z == 1) ? Xk : Xv;
    const f16* Wh = (z == 0) ? Wqh : (z == 1) ? Wkh : Wvh;
    const float* bias = (z == 0) ? bq : (z == 1) ? bk : bv;

    const int m0 = blockIdx.x * 128;
    const int n0 = blockIdx.y * 128;

    const int tid = threadIdx.x;
    const int w = tid >> 6, l = tid & 63;
    const int lp = l >> 4, lq = l & 15;
    const int wm = w >> 1, wn = w & 1;

    f32x4 acc[4][4] = {};

    for (int kt = 0; kt < D_MODEL; kt += 64) {
        __syncthreads();
        float4 av[4][2];
        int arow[4], aslot[4];
#pragma unroll
        for (int j = 0; j < 4; ++j) {
            const int chunk = j * 256 + tid;
            arow[j] = chunk >> 3;
            aslot[j] = chunk & 7;
            const float* sp = X + (size_t)(m0 + arow[j]) * D_MODEL + kt + aslot[j] * 8;
            av[j][0] = *(const float4*)sp;
            av[j][1] = *(const float4*)(sp + 4);
        }
#pragma unroll
        for (int j = 0; j < 4; ++j) {
            const int cb = j * 256 + w * 64;
            const int chunk = cb + l;
            const int row = chunk >> 3;
            const int slot = (chunk & 7) ^ (row & 7);
            GLOAD_LDS16(Wh + (size_t)(n0 + row) * D_MODEL + kt + slot * 8,
                        ldsW + cb * 8);
        }
#pragma unroll
        for (int j = 0; j < 4; ++j) {
            f16x8 hv;
            hv[0] = (f16)av[j][0].x; hv[1] = (f16)av[j][0].y;
            hv[2] = (f16)av[j][0].z; hv[3] = (f16)av[j][0].w;
            hv[4] = (f16)av[j][1].x; hv[5] = (f16)av[j][1].y;
            hv[6] = (f16)av[j][1].z; hv[7] = (f16)av[j][1].w;
            *(f16x8*)(ldsA + arow[j] * 64 + ((aslot[j] ^ (arow[j] & 7)) << 3)) = hv;
        }
        __syncthreads();

        f16x8 af[4][2];
#pragma unroll
        for (int mt = 0; mt < 4; ++mt) {
            const int R = wm * 64 + mt * 16 + lq;
#pragma unroll
            for (int s = 0; s < 2; ++s)
                af[mt][s] = *(const f16x8*)(ldsA + R * 64 + (((s * 4 + lp) ^ (R & 7)) << 3));
        }
        __builtin_amdgcn_s_setprio(1);
#pragma unroll
        for (int nt = 0; nt < 4; ++nt) {
            const int R = wn * 64 + nt * 16 + lq;
            f16x8 b0 = *(const f16x8*)(ldsW + R * 64 + (((0 + lp) ^ (R & 7)) << 3));
            f16x8 b1 = *(const f16x8*)(ldsW + R * 64 + (((4 + lp) ^ (R & 7)) << 3));
#pragma unroll
            for (int mt = 0; mt < 4; ++mt) {
                acc[mt][nt] = MFMA16(af[mt][0], b0, acc[mt][nt]);
                acc[mt][nt] = MFMA16(af[mt][1], b1, acc[mt][nt]);
            }
        }
        __builtin_amdgcn_s_setprio(0);
    }

    const int m_base = m0 + wm * 64;
    const int n_base = n0 + wn * 64;
    const int b = m0 / SEQ;
    const int h = n_base >> 6;
    const size_t bh_ = (size_t)b * N_HEADS + h;

    if (z == 0) {
#pragma unroll
        for (int nt = 0; nt < 4; ++nt) {
            const int n = n_base + nt * 16 + lq;
            const float bn = bias[n];
            const int d = n & 63;
#pragma unroll
            for (int mt = 0; mt < 4; ++mt) {
#pragma unroll
                for (int r = 0; r < 4; ++r) {
                    const int s = (m_base + mt * 16 + lp * 4 + r) & (SEQ - 1);
                    Qh[(bh_ * SEQ + s) * 64 + d] = (f16)((acc[mt][nt][r] + bn) * QSCALE);
                }
            }
        }
    } else if (z == 1) {
#pragma unroll
        for (int nt = 0; nt < 4; ++nt) {
            const int n = n_base + nt * 16 + lq;
            const float bn = bias[n];
            const int d = n & 63;
#pragma unroll
            for (int mt = 0; mt < 4; ++mt) {
#pragma unroll
                for (int r = 0; r < 4; ++r) {
                    const int s = (m_base + mt * 16 + lp * 4 + r) & (SEQ - 1);
                    Kh[(bh_ * SEQ + s) * 64 + d] = (f16)(acc[mt][nt][r] + bn);
                }
            }
        }
    } else {
#pragma unroll
        for (int nt = 0; nt < 4; ++nt) {
            const int n = n_base + nt * 16 + lq;
            const float bn = bias[n];
            const int d = n & 63;
#pragma unroll
            for (int mt = 0; mt < 4; ++mt) {
                const int s0 = (m_base + mt * 16 + lp * 4) & (SEQ - 1);
                f16x4 col;
#pragma unroll
                for (int r = 0; r < 4; ++r)
                    col[r] = (f16)(acc[mt][nt][r] + bn);
                *(f16x4*)(Vt + (bh_ * 64 + d) * SEQ + s0) = col;
            }
        }
    }
}

// ---------------------------------------------------------------------------
// out projection: d_out = G @ Wo^T + bo (fp32 out); Gh + Woh via gload_lds.
// ---------------------------------------------------------------------------
__global__ __launch_bounds__(256, 4) void out_mfma(
    const f16* __restrict__ Gh, const f16* __restrict__ Woh,
    const float* __restrict__ bo, float* __restrict__ Out)
{
    __shared__ f16 ldsA[64 * 64];
    __shared__ f16 ldsW[128 * 64];

    const int m0 = blockIdx.x * 64;
    const int n0 = blockIdx.y * 128;

    const int tid = threadIdx.x;
    const int w = tid >> 6, l = tid & 63;
    const int lp = l >> 4, lq = l & 15;
    const int wm = w >> 1, wn = w & 1;

    f32x4 acc[2][4] = {};

    for (int kt = 0; kt < D_MODEL; kt += 64) {
        __syncthreads();
#pragma unroll
        for (int j = 0; j < 2; ++j) {
            const int cb = j * 256 + w * 64;
            const int chunk = cb + l;
            const int row = chunk >> 3;
            const int slot = (chunk & 7) ^ (row & 7);
            GLOAD_LDS16(Gh + (size_t)(m0 + row) * D_MODEL + kt + slot * 8,
                        ldsA + cb * 8);
        }
#pragma unroll
        for (int j = 0; j < 4; ++j) {
            const int cb = j * 256 + w * 64;
            const int chunk = cb + l;
            const int row = chunk >> 3;
            const int slot = (chunk & 7) ^ (row & 7);
            GLOAD_LDS16(Woh + (size_t)(n0 + row) * D_MODEL + kt + slot * 8,
                        ldsW + cb * 8);
        }
        __syncthreads();

        f16x8 af[2][2];
#pragma unroll
        for (int mt = 0; mt < 2; ++mt) {
            const int R = wm * 32 + mt * 16 + lq;
#pragma unroll
            for (int s = 0; s < 2; ++s)
                af[mt][s] = *(const f16x8*)(ldsA + R * 64 + (((s * 4 + lp) ^ (R & 7)) << 3));
        }
        __builtin_amdgcn_s_setprio(1);
#pragma unroll
        for (int nt = 0; nt < 4; ++nt) {
            const int R = wn * 64 + nt * 16 + lq;
            f16x8 b0 = *(const f16x8*)(ldsW + R * 64 + (((0 + lp) ^ (R & 7)) << 3));
            f16x8 b1 = *(const f16x8*)(ldsW + R * 64 + (((4 + lp) ^ (R & 7)) << 3));
#pragma unroll
            for (int mt = 0; mt < 2; ++mt) {
                acc[mt][nt] = MFMA16(af[mt][0], b0, acc[mt][nt]);
                acc[mt][nt] = MFMA16(af[mt][1], b1, acc[mt][nt]);
            }
        }
        __builtin_amdgcn_s_setprio(0);
    }

#pragma unroll
    for (int nt = 0; nt < 4; ++nt) {
        const int n = n0 + wn * 64 + nt * 16 + lq;
        const float bn = bo[n];
#pragma unroll
        for (int mt = 0; mt < 2; ++mt) {
#pragma unroll
            for (int r = 0; r < 4; ++r) {
                const int m = m0 + wm * 32 + mt * 16 + lp * 4 + r;
                Out[(size_t)m * D_MODEL + n] = acc[mt][nt][r] + bn;
            }
        }
    }
}

// ---------------------------------------------------------------------------
// Flash attention, K-SPLIT partials: grid 1024 (= 4 blocks/CU, 4 waves/SIMD).
// Each block owns 16 k-tiles (split = 0 or 1) of one (bh, 128-q block) and
// accumulates partial o (f16 out) and lf (f32) -- legal because the no-max
// softmax makes tiles linearly separable. Single-tile barrier windows,
// 2x16KB LDS double buffer (32KB -> 4 blocks/CU). P in-register via
// cvt_pkrtz + permlane; row sums via ones-B MFMA; OFFI C-init; invariant
// LDS offsets; strength-reduced staging pointers.
// ---------------------------------------------------------------------------
__global__ __launch_bounds__(256, 4) void flash_part(
    const f16* __restrict__ Qh, const f16* __restrict__ Kh,
    const f16* __restrict__ Vt, f16* __restrict__ Op, float* __restrict__ Lp)
{
    __shared__ f16 KV[2][2][4096];   // [buf][0=K,1=V][64*64], swizzled

    const int tid = threadIdx.x;
    const int w  = tid >> 6;
    const int l  = tid & 63;
    const int lp = l >> 4;
    const int lq = l & 15;

    // XCD-chunked swizzle: 128 consecutive works per XCD -> 4 bh per XCD L2
    const int id = blockIdx.x;
    const int work = (id & 7) * 128 + (id >> 3);
    const int bh = work >> 5;
    const int rest = work & 31;
    const int qblk = rest >> 1;
    const int split = rest & 1;
    const int q0 = qblk * 128 + w * 32;

    // ---- Q B-fragments ----
    f16x8 qf[2][2];
#pragma unroll
    for (int sub = 0; sub < 2; ++sub)
#pragma unroll
        for (int s = 0; s < 2; ++s)
            qf[sub][s] = *(const f16x8*)(Qh + ((size_t)bh * SEQ + q0 + sub * 16 + lq) * 64
                                          + s * 32 + lp * 8);

    f16x8 ones;
#pragma unroll
    for (int i = 0; i < 8; ++i) ones[i] = (f16)1.f;
    const f32x4 OFFI = (f32x4){-OFF2, -OFF2, -OFF2, -OFF2};

    f32x4 o[2][4];
#pragma unroll
    for (int sub = 0; sub < 2; ++sub)
#pragma unroll
        for (int c = 0; c < 4; ++c) o[sub][c] = (f32x4){0.f, 0.f, 0.f, 0.f};
    f32x4 lf[2] = {(f32x4){0.f, 0.f, 0.f, 0.f}, (f32x4){0.f, 0.f, 0.f, 0.f}};

    // ---- loop-invariant LDS byte offsets ----
    int koff[4][2], voff[2][4];
#pragma unroll
    for (int mt = 0; mt < 4; ++mt) {
        const int krow = mt * 16 + lq;
#pragma unroll
        for (int s = 0; s < 2; ++s)
            koff[mt][s] = krow * 128 + (((4 * s + lp) ^ (krow & 7)) << 4);
    }
#pragma unroll
    for (int s = 0; s < 2; ++s)
#pragma unroll
        for (int nt = 0; nt < 4; ++nt) {
            const int d = nt * 16 + lq;
            voff[s][nt] = d * 128 + (((4 * s + lp) ^ (d & 7)) << 4);
        }

    // ---- staging pointers, based at this split's first tile ----
    const int lr0 = w * 8 + (l >> 3);
    const int lr1 = (w + 4) * 8 + (l >> 3);
    const int krow0 = split * 1024;     // 16 tiles x 64 rows
    const f16* kp0 = Kh + ((size_t)bh * SEQ + krow0 + lr0) * 64 + (((l & 7) ^ (lr0 & 7)) << 3);
    const f16* kp1 = Kh + ((size_t)bh * SEQ + krow0 + lr1) * 64 + (((l & 7) ^ (lr1 & 7)) << 3);
    const f16* vp0 = Vt + ((size_t)bh * 64 + lr0) * SEQ + krow0 + (((l & 7) ^ (lr0 & 7)) << 3);
    const f16* vp1 = Vt + ((size_t)bh * 64 + lr1) * SEQ + krow0 + (((l & 7) ^ (lr1 & 7)) << 3);

    auto STAGE = [&](int bf) {
        GLOAD_LDS16(kp0, &KV[bf][0][w * 512]);
        GLOAD_LDS16(kp1, &KV[bf][0][(w + 4) * 512]);
        GLOAD_LDS16(vp0, &KV[bf][1][w * 512]);
        GLOAD_LDS16(vp1, &KV[bf][1][(w + 4) * 512]);
        kp0 += 4096; kp1 += 4096;   // +64 K rows
        vp0 += 64;   vp1 += 64;     // +64 V columns
    };

    auto QKT = [&](int bf, f32x4 (&st)[2][4], f16x8 (&vbr)[2][4]) {
        const char* Kt_ = (const char*)&KV[bf][0][0];
        const char* Vt_ = (const char*)&KV[bf][1][0];
        __builtin_amdgcn_s_setprio(1);
#pragma unroll
        for (int mt = 0; mt < 4; ++mt) {
            f16x8 ah0 = *(const f16x8*)(Kt_ + koff[mt][0]);
            f16x8 ah1 = *(const f16x8*)(Kt_ + koff[mt][1]);
#pragma unroll
            for (int sub = 0; sub < 2; ++sub) {
                st[sub][mt] = MFMA16(ah0, qf[sub][0], OFFI);
                st[sub][mt] = MFMA16(ah1, qf[sub][1], st[sub][mt]);
            }
        }
        __builtin_amdgcn_s_setprio(0);
#pragma unroll
        for (int s = 0; s < 2; ++s)
#pragma unroll
            for (int nt = 0; nt < 4; ++nt)
                vbr[s][nt] = *(const f16x8*)(Vt_ + voff[s][nt]);
    };

    auto SMPV = [&](f32x4 (&st)[2][4], f16x8 (&vbr)[2][4]) {
        f16x8 pa[2][2];
#pragma unroll
        for (int sub = 0; sub < 2; ++sub) {
            unsigned int pk0[4], pk1[4];
#pragma unroll
            for (int mt = 0; mt < 4; ++mt) {
                float e0 = EXP2(st[sub][mt][0]);
                float e1 = EXP2(st[sub][mt][1]);
                float e2 = EXP2(st[sub][mt][2]);
                float e3 = EXP2(st[sub][mt][3]);
                pk0[mt] = __builtin_bit_cast(unsigned int,
                              __builtin_amdgcn_cvt_pkrtz(e0, e1));
                pk1[mt] = __builtin_bit_cast(unsigned int,
                              __builtin_amdgcn_cvt_pkrtz(e2, e3));
            }
#pragma unroll
            for (int s = 0; s < 2; ++s) {
                unsigned int x0 = pk0[2 * s], y0 = pk0[2 * s + 1];
                unsigned int x1 = pk1[2 * s], y1 = pk1[2 * s + 1];
                asm("v_permlane32_swap_b32 %0, %1" : "+v"(x0), "+v"(y0));
                asm("v_permlane16_swap_b32 %0, %1" : "+v"(x0), "+v"(y0));
                asm("v_permlane32_swap_b32 %0, %1" : "+v"(x1), "+v"(y1));
                asm("v_permlane16_swap_b32 %0, %1" : "+v"(x1), "+v"(y1));
                u32x4 t4 = {x0, x1, y0, y1};
                pa[sub][s] = __builtin_bit_cast(f16x8, t4);
            }
        }
        __builtin_amdgcn_s_setprio(1);
#pragma unroll
        for (int s = 0; s < 2; ++s) {
#pragma unroll
            for (int sub = 0; sub < 2; ++sub) {
                lf[sub] = MFMA16(pa[sub][s], ones, lf[sub]);
#pragma unroll
                for (int nt = 0; nt < 4; ++nt)
                    o[sub][nt] = MFMA16(pa[sub][s], vbr[s][nt], o[sub][nt]);
            }
        }
        __builtin_amdgcn_s_setprio(0);
    };

    f32x4 st[2][4];
    f16x8 vbr[2][4];

    STAGE(0);
    int buf = 0;

#pragma unroll 1
    for (int t = 0; t < 16; ++t) {
        asm volatile("s_waitcnt vmcnt(0)" ::: "memory");
        __builtin_amdgcn_s_barrier();
        if (t < 15) STAGE(buf ^ 1);
        __builtin_amdgcn_sched_barrier(0);

        QKT(buf, st, vbr);
        SMPV(st, vbr);
        buf ^= 1;
    }

    // ---- write partials: Op[split][bh][row][64] f16, Lp[split][bh][row] ----
    f16* op = Op + ((size_t)split * 32 + bh) * SEQ * 64;
    float* lpp = Lp + ((size_t)split * 32 + bh) * SEQ;
#pragma unroll
    for (int sub = 0; sub < 2; ++sub) {
#pragma unroll
        for (int j = 0; j < 4; ++j) {
            const int row = q0 + sub * 16 + lp * 4 + j;
#pragma unroll
            for (int nt = 0; nt < 4; ++nt)
                op[(size_t)row * 64 + nt * 16 + lq] = (f16)o[sub][nt][j];
            if (lq == 0) lpp[row] = lf[sub][j];
        }
    }
}

// ---------------------------------------------------------------------------
// combine partials: ctx = (oA+oB)/(lfA+lfB); exact GELU; -> Gh layout
// [b][row][D_MODEL] head-sliced. 4M elems, ~25MB traffic.
// ---------------------------------------------------------------------------
__global__ __launch_bounds__(256) void combine(
    const f16* __restrict__ Op, const float* __restrict__ Lp,
    f16* __restrict__ Gh)
{
    const int i = blockIdx.x * 256 + threadIdx.x;   // 524288 threads
    const int dg = i & 7;
    const int rowg = i >> 3;        // bh*SEQ + row
    const int bh = rowg >> 11;
    const int row = rowg & (SEQ - 1);
    const int b = bh >> 3, h = bh & 7;

    const size_t half = (size_t)32 * SEQ * 8;   // in f16x8 units
    f16x8 a = ((const f16x8*)Op)[(size_t)rowg * 8 + dg];
    f16x8 c = ((const f16x8*)Op)[half + (size_t)rowg * 8 + dg];
    const float inv = 1.f / (Lp[rowg] + Lp[32 * SEQ + rowg]);

    f16x8 g;
#pragma unroll
    for (int k = 0; k < 8; ++k) {
        float x = ((float)a[k] + (float)c[k]) * inv;
        g[k] = (f16)(0.5f * x * (1.f + erff(x * 0.70710678118654752f)));
    }
    ((f16x8*)(Gh + ((size_t)(b * SEQ + row)) * D_MODEL + h * 64))[dg] = g;
}

// ---------------------------------------------------------------------------
extern "C" void kernel_launch(void* const* d_in, const int* in_sizes, int n_in,
                              void* d_out, int out_size, void* d_ws, size_t ws_size,
                              hipStream_t stream)
{
    const float* query = (const float*)d_in[0];
    const float* key   = (const float*)d_in[1];
    const float* value = (const float*)d_in[2];
    const float* Wq = (const float*)d_in[3];
    const float* bq = (const float*)d_in[4];
    const float* Wk = (const float*)d_in[5];
    const float* bk = (const float*)d_in[6];
    const float* Wv = (const float*)d_in[7];
    const float* bv = (const float*)d_in[8];
    const float* Wo = (const float*)d_in[9];
    const float* bo = (const float*)d_in[10];

    char* ws = (char*)d_ws;
    const size_t MB = 1024 * 1024;
    const size_t KB = 1024;
    f16* Qh = (f16*)(ws + 0 * MB);    // 8 MB
    f16* Kh = (f16*)(ws + 8 * MB);    // 8 MB
    f16* Vt = (f16*)(ws + 16 * MB);   // 8 MB
    f16* Gh = (f16*)(ws + 24 * MB);   // 8 MB
    f16* Wqh = (f16*)(ws + 32 * MB);
    f16* Wkh = (f16*)(ws + 32 * MB + 512 * KB);
    f16* Wvh = (f16*)(ws + 33 * MB);
    f16* Woh = (f16*)(ws + 33 * MB + 512 * KB);
    f16* Op  = (f16*)(ws + 34 * MB);  // 16 MB (2 splits x 8 MB)
    float* Lp = (float*)(ws + 50 * MB); // 512 KB

    wsplit<<<dim3(64, 4), 256, 0, stream>>>(Wq, Wk, Wv, Wo, Wqh, Wkh, Wvh, Woh);

    proj_mfma<<<dim3(BATCH * SEQ / 128, D_MODEL / 128, 3), 256, 0, stream>>>(
        query, key, value, Wqh, Wkh, Wvh, bq, bk, bv, Qh, Kh, Vt);

    flash_part<<<dim3(1024), 256, 0, stream>>>(Qh, Kh, Vt, Op, Lp);

    combine<<<dim3(2048), 256, 0, stream>>>(Op, Lp, Gh);

    out_mfma<<<dim3(BATCH * SEQ / 64, D_MODEL / 128), 256, 0, stream>>>(
        Gh, Woh, bo, (float*)d_out);
}

// Round 15
// 84.325 us; speedup vs baseline: 1.1293x; 1.1293x over previous
//
#include <hip/hip_runtime.h>
#include <hip/hip_bf16.h>

#define D_MODEL 512
#define N_HEADS 8
#define HEAD_DIM 64
#define BATCH 4
#define SEQ 2048

typedef _Float16 f16;
typedef _Float16 f16x8 __attribute__((ext_vector_type(8)));
typedef _Float16 f16x4 __attribute__((ext_vector_type(4)));
typedef float f32x4 __attribute__((ext_vector_type(4)));
typedef unsigned int u32x4 __attribute__((ext_vector_type(4)));

#define MFMA16(a, b, c) __builtin_amdgcn_mfma_f32_16x16x32_f16((a), (b), (c), 0, 0, 0)

#define GLOAD_LDS16(src, dst)                                                   \
    __builtin_amdgcn_global_load_lds(                                           \
        (const __attribute__((address_space(1))) void*)(src),                   \
        (__attribute__((address_space(3))) void*)(dst), 16, 0, 0)

#if __has_builtin(__builtin_amdgcn_exp2f)
#define EXP2(x) __builtin_amdgcn_exp2f(x)
#else
#define EXP2(x) __expf((x) * 0.6931471805599453f)
#endif

// Q pre-scale: 1/sqrt(64) * log2(e)  (scores produced in log2 domain)
#define QSCALE 0.18033688011112042f
// softmax offset: 6 * log2(e)
#define OFF2 8.656170245333781f

// ---------------------------------------------------------------------------
// weights fp32 -> f16 (hi only): Wq, Wk, Wv, Wo
// ---------------------------------------------------------------------------
__global__ __launch_bounds__(256) void wsplit(
    const float* __restrict__ w0, const float* __restrict__ w1,
    const float* __restrict__ w2, const float* __restrict__ w3,
    f16* __restrict__ h0, f16* __restrict__ h1,
    f16* __restrict__ h2, f16* __restrict__ h3)
{
    const int j = blockIdx.y;
    const float* s = (j == 0) ? w0 : (j == 1) ? w1 : (j == 2) ? w2 : w3;
    f16* dh = (j == 0) ? h0 : (j == 1) ? h1 : (j == 2) ? h2 : h3;
    const int n4 = (D_MODEL * D_MODEL) >> 2;
    for (int i = blockIdx.x * 256 + threadIdx.x; i < n4; i += gridDim.x * 256) {
        float4 x = ((const float4*)s)[i];
        f16x4 hv = {(f16)x.x, (f16)x.y, (f16)x.z, (f16)x.w};
        ((f16x4*)dh)[i] = hv;
    }
}

// ---------------------------------------------------------------------------
// QKV projection (BM=128/BN=128, 256 thr, grid 768 = 3 blocks/CU).
// A reg-staged fp32->f16; W f16 via global_load_lds (pre-swizzled source).
// ---------------------------------------------------------------------------
__global__ __launch_bounds__(256, 3) void proj_mfma(
    const float* __restrict__ Xq, const float* __restrict__ Xk,
    const float* __restrict__ Xv,
    const f16* __restrict__ Wqh, const f16* __restrict__ Wkh,
    const f16* __restrict__ Wvh,
    const float* __restrict__ bq, const float* __restrict__ bk,
    const float* __restrict__ bv,
    f16* __restrict__ Qh, f16* __restrict__ Kh, f16* __restrict__ Vt)
{
    __shared__ f16 ldsA[128 * 64];
    __shared__ f16 ldsW[128 * 64];

    const int z = blockIdx.z;
    const float* X = (z == 0) ? Xq : (z == 1) ? Xk : Xv;
    const f16* Wh = (z == 0) ? Wqh : (z == 1) ? Wkh : Wvh;
    const float* bias = (z == 0) ? bq : (z == 1) ? bk : bv;

    const int m0 = blockIdx.x * 128;
    const int n0 = blockIdx.y * 128;

    const int tid = threadIdx.x;
    const int w = tid >> 6, l = tid & 63;
    const int lp = l >> 4, lq = l & 15;
    const int wm = w >> 1, wn = w & 1;

    f32x4 acc[4][4] = {};

    for (int kt = 0; kt < D_MODEL; kt += 64) {
        __syncthreads();
        float4 av[4][2];
        int arow[4], aslot[4];
#pragma unroll
        for (int j = 0; j < 4; ++j) {
            const int chunk = j * 256 + tid;
            arow[j] = chunk >> 3;
            aslot[j] = chunk & 7;
            const float* sp = X + (size_t)(m0 + arow[j]) * D_MODEL + kt + aslot[j] * 8;
            av[j][0] = *(const float4*)sp;
            av[j][1] = *(const float4*)(sp + 4);
        }
#pragma unroll
        for (int j = 0; j < 4; ++j) {
            const int cb = j * 256 + w * 64;
            const int chunk = cb + l;
            const int row = chunk >> 3;
            const int slot = (chunk & 7) ^ (row & 7);
            GLOAD_LDS16(Wh + (size_t)(n0 + row) * D_MODEL + kt + slot * 8,
                        ldsW + cb * 8);
        }
#pragma unroll
        for (int j = 0; j < 4; ++j) {
            f16x8 hv;
            hv[0] = (f16)av[j][0].x; hv[1] = (f16)av[j][0].y;
            hv[2] = (f16)av[j][0].z; hv[3] = (f16)av[j][0].w;
            hv[4] = (f16)av[j][1].x; hv[5] = (f16)av[j][1].y;
            hv[6] = (f16)av[j][1].z; hv[7] = (f16)av[j][1].w;
            *(f16x8*)(ldsA + arow[j] * 64 + ((aslot[j] ^ (arow[j] & 7)) << 3)) = hv;
        }
        __syncthreads();

        f16x8 af[4][2];
#pragma unroll
        for (int mt = 0; mt < 4; ++mt) {
            const int R = wm * 64 + mt * 16 + lq;
#pragma unroll
            for (int s = 0; s < 2; ++s)
                af[mt][s] = *(const f16x8*)(ldsA + R * 64 + (((s * 4 + lp) ^ (R & 7)) << 3));
        }
        __builtin_amdgcn_s_setprio(1);
#pragma unroll
        for (int nt = 0; nt < 4; ++nt) {
            const int R = wn * 64 + nt * 16 + lq;
            f16x8 b0 = *(const f16x8*)(ldsW + R * 64 + (((0 + lp) ^ (R & 7)) << 3));
            f16x8 b1 = *(const f16x8*)(ldsW + R * 64 + (((4 + lp) ^ (R & 7)) << 3));
#pragma unroll
            for (int mt = 0; mt < 4; ++mt) {
                acc[mt][nt] = MFMA16(af[mt][0], b0, acc[mt][nt]);
                acc[mt][nt] = MFMA16(af[mt][1], b1, acc[mt][nt]);
            }
        }
        __builtin_amdgcn_s_setprio(0);
    }

    const int m_base = m0 + wm * 64;
    const int n_base = n0 + wn * 64;
    const int b = m0 / SEQ;
    const int h = n_base >> 6;
    const size_t bh_ = (size_t)b * N_HEADS + h;

    if (z == 0) {
#pragma unroll
        for (int nt = 0; nt < 4; ++nt) {
            const int n = n_base + nt * 16 + lq;
            const float bn = bias[n];
            const int d = n & 63;
#pragma unroll
            for (int mt = 0; mt < 4; ++mt) {
#pragma unroll
                for (int r = 0; r < 4; ++r) {
                    const int s = (m_base + mt * 16 + lp * 4 + r) & (SEQ - 1);
                    Qh[(bh_ * SEQ + s) * 64 + d] = (f16)((acc[mt][nt][r] + bn) * QSCALE);
                }
            }
        }
    } else if (z == 1) {
#pragma unroll
        for (int nt = 0; nt < 4; ++nt) {
            const int n = n_base + nt * 16 + lq;
            const float bn = bias[n];
            const int d = n & 63;
#pragma unroll
            for (int mt = 0; mt < 4; ++mt) {
#pragma unroll
                for (int r = 0; r < 4; ++r) {
                    const int s = (m_base + mt * 16 + lp * 4 + r) & (SEQ - 1);
                    Kh[(bh_ * SEQ + s) * 64 + d] = (f16)(acc[mt][nt][r] + bn);
                }
            }
        }
    } else {
#pragma unroll
        for (int nt = 0; nt < 4; ++nt) {
            const int n = n_base + nt * 16 + lq;
            const float bn = bias[n];
            const int d = n & 63;
#pragma unroll
            for (int mt = 0; mt < 4; ++mt) {
                const int s0 = (m_base + mt * 16 + lp * 4) & (SEQ - 1);
                f16x4 col;
#pragma unroll
                for (int r = 0; r < 4; ++r)
                    col[r] = (f16)(acc[mt][nt][r] + bn);
                *(f16x4*)(Vt + (bh_ * 64 + d) * SEQ + s0) = col;
            }
        }
    }
}

// ---------------------------------------------------------------------------
// out projection: d_out = G @ Wo^T + bo (fp32 out); Gh + Woh via gload_lds.
// ---------------------------------------------------------------------------
__global__ __launch_bounds__(256, 4) void out_mfma(
    const f16* __restrict__ Gh, const f16* __restrict__ Woh,
    const float* __restrict__ bo, float* __restrict__ Out)
{
    __shared__ f16 ldsA[64 * 64];
    __shared__ f16 ldsW[128 * 64];

    const int m0 = blockIdx.x * 64;
    const int n0 = blockIdx.y * 128;

    const int tid = threadIdx.x;
    const int w = tid >> 6, l = tid & 63;
    const int lp = l >> 4, lq = l & 15;
    const int wm = w >> 1, wn = w & 1;

    f32x4 acc[2][4] = {};

    for (int kt = 0; kt < D_MODEL; kt += 64) {
        __syncthreads();
#pragma unroll
        for (int j = 0; j < 2; ++j) {
            const int cb = j * 256 + w * 64;
            const int chunk = cb + l;
            const int row = chunk >> 3;
            const int slot = (chunk & 7) ^ (row & 7);
            GLOAD_LDS16(Gh + (size_t)(m0 + row) * D_MODEL + kt + slot * 8,
                        ldsA + cb * 8);
        }
#pragma unroll
        for (int j = 0; j < 4; ++j) {
            const int cb = j * 256 + w * 64;
            const int chunk = cb + l;
            const int row = chunk >> 3;
            const int slot = (chunk & 7) ^ (row & 7);
            GLOAD_LDS16(Woh + (size_t)(n0 + row) * D_MODEL + kt + slot * 8,
                        ldsW + cb * 8);
        }
        __syncthreads();

        f16x8 af[2][2];
#pragma unroll
        for (int mt = 0; mt < 2; ++mt) {
            const int R = wm * 32 + mt * 16 + lq;
#pragma unroll
            for (int s = 0; s < 2; ++s)
                af[mt][s] = *(const f16x8*)(ldsA + R * 64 + (((s * 4 + lp) ^ (R & 7)) << 3));
        }
        __builtin_amdgcn_s_setprio(1);
#pragma unroll
        for (int nt = 0; nt < 4; ++nt) {
            const int R = wn * 64 + nt * 16 + lq;
            f16x8 b0 = *(const f16x8*)(ldsW + R * 64 + (((0 + lp) ^ (R & 7)) << 3));
            f16x8 b1 = *(const f16x8*)(ldsW + R * 64 + (((4 + lp) ^ (R & 7)) << 3));
#pragma unroll
            for (int mt = 0; mt < 2; ++mt) {
                acc[mt][nt] = MFMA16(af[mt][0], b0, acc[mt][nt]);
                acc[mt][nt] = MFMA16(af[mt][1], b1, acc[mt][nt]);
            }
        }
        __builtin_amdgcn_s_setprio(0);
    }

#pragma unroll
    for (int nt = 0; nt < 4; ++nt) {
        const int n = n0 + wn * 64 + nt * 16 + lq;
        const float bn = bo[n];
#pragma unroll
        for (int mt = 0; mt < 2; ++mt) {
#pragma unroll
            for (int r = 0; r < 4; ++r) {
                const int m = m0 + wm * 32 + mt * 16 + lp * 4 + r;
                Out[(size_t)m * D_MODEL + n] = acc[mt][nt][r] + bn;
            }
        }
    }
}

// ---------------------------------------------------------------------------
// MFMA flash attention + fused exact GELU (best measured: r11 structure).
// TWO k-tiles per barrier window: 4 LDS buffers (64KB, 2 blocks/CU), 16
// windows of {vmcnt(0); barrier; stage next pair; QKT(e); QKT(o); SMPV(e);
// SMPV(o)}. 128 q-rows/block, 4 waves x 32 q-rows; grid 512.
// P stays in-register (cvt_pkrtz + permlane); row sums via ones-B MFMA.
// ---------------------------------------------------------------------------
__global__ __launch_bounds__(256, 2) void flash_mfma(
    const f16* __restrict__ Qh, const f16* __restrict__ Kh,
    const f16* __restrict__ Vt, f16* __restrict__ Gh)
{
    __shared__ f16 KV[4][2][4096];   // [buf][0=K,1=V][64*64], swizzled

    const int tid = threadIdx.x;
    const int w  = tid >> 6;
    const int l  = tid & 63;
    const int lp = l >> 4;
    const int lq = l & 15;

    // XCD-chunked swizzle: 64 consecutive works per XCD -> 4 bh per XCD L2
    const int id = blockIdx.x;
    const int work = (id & 7) * 64 + (id >> 3);
    const int bh = work >> 4;
    const int b  = bh >> 3, h = bh & 7;
    const int q0 = (work & 15) * 128 + w * 32;   // this wave's 32 q-rows

    // ---- Q B-fragments (pre-scaled by QSCALE in projection) ----
    f16x8 qf[2][2];   // [sub][s]
#pragma unroll
    for (int sub = 0; sub < 2; ++sub)
#pragma unroll
        for (int s = 0; s < 2; ++s)
            qf[sub][s] = *(const f16x8*)(Qh + ((size_t)bh * SEQ + q0 + sub * 16 + lq) * 64
                                          + s * 32 + lp * 8);

    f16x8 ones;
#pragma unroll
    for (int i = 0; i < 8; ++i) ones[i] = (f16)1.f;
    const f32x4 OFFI = (f32x4){-OFF2, -OFF2, -OFF2, -OFF2};

    f32x4 o[2][4];
#pragma unroll
    for (int sub = 0; sub < 2; ++sub)
#pragma unroll
        for (int c = 0; c < 4; ++c) o[sub][c] = (f32x4){0.f, 0.f, 0.f, 0.f};
    f32x4 lf[2] = {(f32x4){0.f, 0.f, 0.f, 0.f}, (f32x4){0.f, 0.f, 0.f, 0.f}};

    // ---- loop-invariant LDS byte offsets ----
    int koff[4][2], voff[2][4];
#pragma unroll
    for (int mt = 0; mt < 4; ++mt) {
        const int krow = mt * 16 + lq;
#pragma unroll
        for (int s = 0; s < 2; ++s)
            koff[mt][s] = krow * 128 + (((4 * s + lp) ^ (krow & 7)) << 4);
    }
#pragma unroll
    for (int s = 0; s < 2; ++s)
#pragma unroll
        for (int nt = 0; nt < 4; ++nt) {
            const int d = nt * 16 + lq;
            voff[s][nt] = d * 128 + (((4 * s + lp) ^ (d & 7)) << 4);
        }

    // ---- strength-reduced staging pointers (wave stages chunks w, w+4) ----
    const int lr0 = w * 8 + (l >> 3);
    const int lr1 = (w + 4) * 8 + (l >> 3);
    const f16* kp0 = Kh + ((size_t)bh * SEQ + lr0) * 64 + (((l & 7) ^ (lr0 & 7)) << 3);
    const f16* kp1 = Kh + ((size_t)bh * SEQ + lr1) * 64 + (((l & 7) ^ (lr1 & 7)) << 3);
    const f16* vp0 = Vt + ((size_t)bh * 64 + lr0) * SEQ + (((l & 7) ^ (lr0 & 7)) << 3);
    const f16* vp1 = Vt + ((size_t)bh * 64 + lr1) * SEQ + (((l & 7) ^ (lr1 & 7)) << 3);

    // stage tiles (2t, 2t+1) into buffer pair {pr*2, pr*2+1}
    auto STAGE_PAIR = [&](int pr) {
        f16* KA = &KV[pr * 2][0][0];
        f16* VA = &KV[pr * 2][1][0];
        f16* KB = &KV[pr * 2 + 1][0][0];
        f16* VB = &KV[pr * 2 + 1][1][0];
        GLOAD_LDS16(kp0, KA + w * 512);
        GLOAD_LDS16(kp1, KA + (w + 4) * 512);
        GLOAD_LDS16(vp0, VA + w * 512);
        GLOAD_LDS16(vp1, VA + (w + 4) * 512);
        GLOAD_LDS16(kp0 + 4096, KB + w * 512);
        GLOAD_LDS16(kp1 + 4096, KB + (w + 4) * 512);
        GLOAD_LDS16(vp0 + 64, VB + w * 512);
        GLOAD_LDS16(vp1 + 64, VB + (w + 4) * 512);
        kp0 += 8192; kp1 += 8192;   // +128 K rows
        vp0 += 128;  vp1 += 128;    // +128 V columns
    };

    // QK^T (swapped, 1-pass, log2 domain; OFFI as first C) + V-frag load
    auto QKT = [&](int bf, f32x4 (&st)[2][4], f16x8 (&vbr)[2][4]) {
        const char* Kt_ = (const char*)&KV[bf][0][0];
        const char* Vt_ = (const char*)&KV[bf][1][0];
        __builtin_amdgcn_s_setprio(1);
#pragma unroll
        for (int mt = 0; mt < 4; ++mt) {
            f16x8 ah0 = *(const f16x8*)(Kt_ + koff[mt][0]);
            f16x8 ah1 = *(const f16x8*)(Kt_ + koff[mt][1]);
#pragma unroll
            for (int sub = 0; sub < 2; ++sub) {
                st[sub][mt] = MFMA16(ah0, qf[sub][0], OFFI);
                st[sub][mt] = MFMA16(ah1, qf[sub][1], st[sub][mt]);
            }
        }
        __builtin_amdgcn_s_setprio(0);
#pragma unroll
        for (int s = 0; s < 2; ++s)
#pragma unroll
            for (int nt = 0; nt < 4; ++nt)
                vbr[s][nt] = *(const f16x8*)(Vt_ + voff[s][nt]);
    };

    // softmax + P-conversion + PV for a saved state
    auto SMPV = [&](f32x4 (&st)[2][4], f16x8 (&vbr)[2][4]) {
        f16x8 pa[2][2];
#pragma unroll
        for (int sub = 0; sub < 2; ++sub) {
            unsigned int pk0[4], pk1[4];
#pragma unroll
            for (int mt = 0; mt < 4; ++mt) {
                float e0 = EXP2(st[sub][mt][0]);
                float e1 = EXP2(st[sub][mt][1]);
                float e2 = EXP2(st[sub][mt][2]);
                float e3 = EXP2(st[sub][mt][3]);
                pk0[mt] = __builtin_bit_cast(unsigned int,
                              __builtin_amdgcn_cvt_pkrtz(e0, e1));
                pk1[mt] = __builtin_bit_cast(unsigned int,
                              __builtin_amdgcn_cvt_pkrtz(e2, e3));
            }
#pragma unroll
            for (int s = 0; s < 2; ++s) {
                unsigned int x0 = pk0[2 * s], y0 = pk0[2 * s + 1];
                unsigned int x1 = pk1[2 * s], y1 = pk1[2 * s + 1];
                asm("v_permlane32_swap_b32 %0, %1" : "+v"(x0), "+v"(y0));
                asm("v_permlane16_swap_b32 %0, %1" : "+v"(x0), "+v"(y0));
                asm("v_permlane32_swap_b32 %0, %1" : "+v"(x1), "+v"(y1));
                asm("v_permlane16_swap_b32 %0, %1" : "+v"(x1), "+v"(y1));
                u32x4 t4 = {x0, x1, y0, y1};
                pa[sub][s] = __builtin_bit_cast(f16x8, t4);
            }
        }
        __builtin_amdgcn_s_setprio(1);
#pragma unroll
        for (int s = 0; s < 2; ++s) {
#pragma unroll
            for (int sub = 0; sub < 2; ++sub) {
                lf[sub] = MFMA16(pa[sub][s], ones, lf[sub]);
#pragma unroll
                for (int nt = 0; nt < 4; ++nt)
                    o[sub][nt] = MFMA16(pa[sub][s], vbr[s][nt], o[sub][nt]);
            }
        }
        __builtin_amdgcn_s_setprio(0);
    };

    f32x4 stE[2][4], stO[2][4];
    f16x8 vbrE[2][4], vbrO[2][4];

    // ---- prologue: stage tiles 0,1 into pair 0 ----
    STAGE_PAIR(0);
    int pr = 0;

    // ---- 16 windows of 2 tiles ----
#pragma unroll 1
    for (int t = 0; t < 16; ++t) {
        asm volatile("s_waitcnt vmcnt(0)" ::: "memory");
        __builtin_amdgcn_s_barrier();
        if (t < 15) STAGE_PAIR(pr ^ 1);
        __builtin_amdgcn_sched_barrier(0);

        QKT(pr * 2, stE, vbrE);
        QKT(pr * 2 + 1, stO, vbrO);
        SMPV(stE, vbrE);
        SMPV(stO, vbrO);

        pr ^= 1;
    }

    // ---- normalize, exact GELU, store Gh ----
#pragma unroll
    for (int sub = 0; sub < 2; ++sub) {
#pragma unroll
        for (int j = 0; j < 4; ++j) {
            const float inv = 1.f / lf[sub][j];
            const int row = q0 + sub * 16 + lp * 4 + j;
#pragma unroll
            for (int nt = 0; nt < 4; ++nt) {
                float x = o[sub][nt][j] * inv;
                float g = 0.5f * x * (1.f + erff(x * 0.70710678118654752f));
                Gh[((size_t)(b * SEQ + row)) * D_MODEL + h * 64 + nt * 16 + lq] = (f16)g;
            }
        }
    }
}

// ---------------------------------------------------------------------------
extern "C" void kernel_launch(void* const* d_in, const int* in_sizes, int n_in,
                              void* d_out, int out_size, void* d_ws, size_t ws_size,
                              hipStream_t stream)
{
    const float* query = (const float*)d_in[0];
    const float* key   = (const float*)d_in[1];
    const float* value = (const float*)d_in[2];
    const float* Wq = (const float*)d_in[3];
    const float* bq = (const float*)d_in[4];
    const float* Wk = (const float*)d_in[5];
    const float* bk = (const float*)d_in[6];
    const float* Wv = (const float*)d_in[7];
    const float* bv = (const float*)d_in[8];
    const float* Wo = (const float*)d_in[9];
    const float* bo = (const float*)d_in[10];

    char* ws = (char*)d_ws;
    const size_t MB = 1024 * 1024;
    const size_t KB = 1024;
    f16* Qh = (f16*)(ws + 0 * MB);    // 8 MB
    f16* Kh = (f16*)(ws + 8 * MB);    // 8 MB
    f16* Vt = (f16*)(ws + 16 * MB);   // 8 MB
    f16* Gh = (f16*)(ws + 24 * MB);   // 8 MB
    f16* Wqh = (f16*)(ws + 32 * MB);
    f16* Wkh = (f16*)(ws + 32 * MB + 512 * KB);
    f16* Wvh = (f16*)(ws + 33 * MB);
    f16* Woh = (f16*)(ws + 33 * MB + 512 * KB);

    wsplit<<<dim3(64, 4), 256, 0, stream>>>(Wq, Wk, Wv, Wo, Wqh, Wkh, Wvh, Woh);

    proj_mfma<<<dim3(BATCH * SEQ / 128, D_MODEL / 128, 3), 256, 0, stream>>>(
        query, key, value, Wqh, Wkh, Wvh, bq, bk, bv, Qh, Kh, Vt);

    flash_mfma<<<dim3(512), 256, 0, stream>>>(Qh, Kh, Vt, Gh);

    out_mfma<<<dim3(BATCH * SEQ / 64, D_MODEL / 128), 256, 0, stream>>>(
        Gh, Woh, bo, (float*)d_out);
}